// Round 5
// baseline (97.303 us; speedup 1.0000x reference)
//
#include <hip/hip_runtime.h>

// 2D RoPE: x (B=8, H=16, N=4096, C=128) fp32, out-of-place.
// R = 32. Quarters: x0=[0:32), x1=[32:64), x2=[64:96), x3=[96:128).
// y0 = x0*rcos - x1*rsin ; y1 = x0*rsin + x1*rcos   (row tables)
// y2 = x2*ccos - x3*csin ; y3 = x2*csin + x3*ccos   (col tables)
// row_cs/col_cs: (64, 32, 2) fp32, [..,0]=cos, [..,1]=sin.
//
// Key invariant: grid stride per iteration = 524288 threads -> rowid stride
// 65536, a multiple of NPOS=4096. So n, t, idx, and the table values are
// IDENTICAL across all 8 iterations of a thread -> hoist them manually
// (compiler can't prove it through the shift/mask). Loop body is then pure
// copy-shaped: 4 NT loads + FMAs + 4 NT stores.

typedef float fv4 __attribute__((ext_vector_type(4)));
typedef float fv8 __attribute__((ext_vector_type(8)));

#define NPOS 4096           // GRID_H * GRID_W
#define F4_PER_ROW 32       // 128 floats / 4
#define NBLOCK 2048
#define NTHREAD (NBLOCK * 256)          // 524288
#define TOTAL_ITEMS (8 * 16 * NPOS * 8) // rows * 8 = 4194304
#define ITERS (TOTAL_ITEMS / NTHREAD)   // 8
#define BASE_STEP ((NTHREAD / 8) * F4_PER_ROW)  // 2097152 float4s per iter

__global__ __launch_bounds__(256)
void rope2d_kernel(const fv4* __restrict__ x,
                   const int* __restrict__ idx,
                   const fv8* __restrict__ row_cs,   // per pos: 8 fv8 (64 floats)
                   const fv8* __restrict__ col_cs,
                   fv4*       __restrict__ out)
{
    const int tid0  = blockIdx.x * 256 + threadIdx.x;
    const int rowid = tid0 >> 3;
    const int t     = tid0 & 7;               // float4 lane within quarter
    const int n     = rowid & (NPOS - 1);     // position (loop-invariant)

    const int id   = idx[n];
    const int prow = id >> 16;
    const int pcol = id & 0xffff;

    // rc = (cos r, sin r, cos r+1, sin r+1, cos r+2, sin r+2, cos r+3, sin r+3)
    const fv8 rc = row_cs[prow * 8 + t];
    const fv8 cc = col_cs[pcol * 8 + t];

    int base = rowid * F4_PER_ROW + t;

    #pragma unroll 4
    for (int i = 0; i < ITERS; ++i, base += BASE_STEP) {
        const fv4 x0 = __builtin_nontemporal_load(x + base);
        const fv4 x1 = __builtin_nontemporal_load(x + base + 8);
        const fv4 x2 = __builtin_nontemporal_load(x + base + 16);
        const fv4 x3 = __builtin_nontemporal_load(x + base + 24);

        fv4 y0, y1, y2, y3;
        y0.x = x0.x * rc.s0 - x1.x * rc.s1;   y1.x = x0.x * rc.s1 + x1.x * rc.s0;
        y0.y = x0.y * rc.s2 - x1.y * rc.s3;   y1.y = x0.y * rc.s3 + x1.y * rc.s2;
        y0.z = x0.z * rc.s4 - x1.z * rc.s5;   y1.z = x0.z * rc.s5 + x1.z * rc.s4;
        y0.w = x0.w * rc.s6 - x1.w * rc.s7;   y1.w = x0.w * rc.s7 + x1.w * rc.s6;

        y2.x = x2.x * cc.s0 - x3.x * cc.s1;   y3.x = x2.x * cc.s1 + x3.x * cc.s0;
        y2.y = x2.y * cc.s2 - x3.y * cc.s3;   y3.y = x2.y * cc.s3 + x3.y * cc.s2;
        y2.z = x2.z * cc.s4 - x3.z * cc.s5;   y3.z = x2.z * cc.s5 + x3.z * cc.s4;
        y2.w = x2.w * cc.s6 - x3.w * cc.s7;   y3.w = x2.w * cc.s7 + x3.w * cc.s6;

        __builtin_nontemporal_store(y0, out + base);
        __builtin_nontemporal_store(y1, out + base + 8);
        __builtin_nontemporal_store(y2, out + base + 16);
        __builtin_nontemporal_store(y3, out + base + 24);
    }
}

extern "C" void kernel_launch(void* const* d_in, const int* in_sizes, int n_in,
                              void* d_out, int out_size, void* d_ws, size_t ws_size,
                              hipStream_t stream) {
    const fv4* x      = (const fv4*)d_in[0];
    const int* idx    = (const int*)d_in[1];
    const fv8* row_cs = (const fv8*)d_in[2];
    const fv8* col_cs = (const fv8*)d_in[3];
    fv4*       out    = (fv4*)d_out;

    rope2d_kernel<<<NBLOCK, 256, 0, stream>>>(x, idx, row_cs, col_cs, out);
}

// Round 6
// 89.735 us; speedup vs baseline: 1.0843x; 1.0843x over previous
//
#include <hip/hip_runtime.h>

// 2D RoPE: x (B=8, H=16, N=4096, C=128) fp32, out-of-place.
// R = 32. Quarters: x0=[0:32), x1=[32:64), x2=[64:96), x3=[96:128).
// y0 = x0*rcos - x1*rsin ; y1 = x0*rsin + x1*rcos   (row tables)
// y2 = x2*ccos - x3*csin ; y3 = x2*csin + x3*ccos   (col tables)
// row_cs/col_cs: (64, 32, 2) fp32, [..,0]=cos, [..,1]=sin.
//
// R4 structure (best: 94.5 us) with ONE change: exact grid, no loop.
// One thread = one 16-float chunk: 4 NT fv4 loads + 4 table loads (L1-hit)
// + FMAs + 4 NT fv4 stores. 16384 blocks x 256 threads.
// History: table amortization (R2) and table hoisting (R5) both regressed —
// cached table loads are free; NT payload hints (+5.5%) are the only real win.

typedef float fv4 __attribute__((ext_vector_type(4)));

#define NPOS 4096           // GRID_H * GRID_W
#define F4_PER_ROW 32       // 128 floats / 4
#define TOTAL_ITEMS (8 * 16 * NPOS * 8) // rows * 8 = 4194304
#define NBLOCK (TOTAL_ITEMS / 256)      // 16384

__global__ __launch_bounds__(256)
void rope2d_kernel(const fv4* __restrict__ x,
                   const int* __restrict__ idx,
                   const fv4* __restrict__ row_cs,   // per pos: 16 fv4 (64 floats)
                   const fv4* __restrict__ col_cs,
                   fv4*       __restrict__ out)
{
    const int g     = blockIdx.x * 256 + threadIdx.x;
    const int rowid = g >> 3;              // which (b,h,n) row
    const int t     = g & 7;               // float4 lane within quarter
    const int n     = rowid & (NPOS - 1);  // position

    const int id   = idx[n];
    const int prow = id >> 16;
    const int pcol = id & 0xffff;

    const int base = rowid * F4_PER_ROW + t;

    const fv4 x0 = __builtin_nontemporal_load(x + base);
    const fv4 x1 = __builtin_nontemporal_load(x + base + 8);
    const fv4 x2 = __builtin_nontemporal_load(x + base + 16);
    const fv4 x3 = __builtin_nontemporal_load(x + base + 24);

    // rcs0 = (cos r, sin r, cos r+1, sin r+1), rcs1 = (cos r+2, sin r+2, cos r+3, sin r+3)
    const fv4 rcs0 = row_cs[prow * 16 + t * 2];
    const fv4 rcs1 = row_cs[prow * 16 + t * 2 + 1];
    const fv4 ccs0 = col_cs[pcol * 16 + t * 2];
    const fv4 ccs1 = col_cs[pcol * 16 + t * 2 + 1];

    fv4 y0, y1, y2, y3;
    y0.x = x0.x * rcs0.x - x1.x * rcs0.y;   y1.x = x0.x * rcs0.y + x1.x * rcs0.x;
    y0.y = x0.y * rcs0.z - x1.y * rcs0.w;   y1.y = x0.y * rcs0.w + x1.y * rcs0.z;
    y0.z = x0.z * rcs1.x - x1.z * rcs1.y;   y1.z = x0.z * rcs1.y + x1.z * rcs1.x;
    y0.w = x0.w * rcs1.z - x1.w * rcs1.w;   y1.w = x0.w * rcs1.w + x1.w * rcs1.z;

    y2.x = x2.x * ccs0.x - x3.x * ccs0.y;   y3.x = x2.x * ccs0.y + x3.x * ccs0.x;
    y2.y = x2.y * ccs0.z - x3.y * ccs0.w;   y3.y = x2.y * ccs0.w + x3.y * ccs0.z;
    y2.z = x2.z * ccs1.x - x3.z * ccs1.y;   y3.z = x2.z * ccs1.y + x3.z * ccs1.x;
    y2.w = x2.w * ccs1.z - x3.w * ccs1.w;   y3.w = x2.w * ccs1.w + x3.w * ccs1.z;

    __builtin_nontemporal_store(y0, out + base);
    __builtin_nontemporal_store(y1, out + base + 8);
    __builtin_nontemporal_store(y2, out + base + 16);
    __builtin_nontemporal_store(y3, out + base + 24);
}

extern "C" void kernel_launch(void* const* d_in, const int* in_sizes, int n_in,
                              void* d_out, int out_size, void* d_ws, size_t ws_size,
                              hipStream_t stream) {
    const fv4* x      = (const fv4*)d_in[0];
    const int* idx    = (const int*)d_in[1];
    const fv4* row_cs = (const fv4*)d_in[2];
    const fv4* col_cs = (const fv4*)d_in[3];
    fv4*       out    = (fv4*)d_out;

    rope2d_kernel<<<NBLOCK, 256, 0, stream>>>(x, idx, row_cs, col_cs, out);
}